// Round 2
// baseline (352.533 us; speedup 1.0000x reference)
//
#include <hip/hip_runtime.h>

// GRU: B=8192, T=1024, I=3, H=4, fp32.
// R5: 2 recurrence waves per SIMD via 12-wave megablocks.
//   R3/R4 forensics: per-chain-step issue I~82cy, serial chain latency L~204cy
//   (4 dependent transcendentals). One wave/SIMD pays I+L=286cy/step; compiler
//   ILP across 2 chains in one wave failed (R4). Fix: HW multithreading —
//   co-locate 2 rec waves per SIMD so the wave scheduler fills stalls.
// 64 blocks x 768 threads (12 waves), 128 batches/block, 1 block/CU (135KB LDS).
//   wid%3!=2 -> rec wave (8/block, 16 chains each); wid%3==2 -> helper (4/block).
//   Under wid%4 SIMD round-robin AND sequential placement, every SIMD gets
//   exactly 2 rec + 1 helper.
// Per-step math is BIT-IDENTICAL to R3 (absmax must reproduce 0.00390625).
// Weights pre-scaled (-log2e for r,z; 2log2e for n) => act = rcp(1+exp2(a)).

#define TC 8            // timesteps per chunk (128 chunks)
#define NB 128          // batches per block
#define OS_W 36         // out_s row: 32 h-floats + 4 pad (keeps b128 flush clean)

template<int CTRL>
__device__ __forceinline__ float dpp_rot(float v) {
    int i = __builtin_bit_cast(int, v);
    int r = __builtin_amdgcn_mov_dpp(i, CTRL, 0xf, 0xf, true);
    return __builtin_bit_cast(float, r);
}
__device__ __forceinline__ float vrcp(float x)  { return __builtin_amdgcn_rcpf(x); }
__device__ __forceinline__ float vexp2(float x) { return __builtin_amdgcn_exp2f(x); }

__global__ __launch_bounds__(768) void gru_kernel(
    const float* __restrict__ x,     // [B, T, 3]
    const float* __restrict__ w_ih,  // [12, 3]
    const float* __restrict__ w_hh,  // [12, 4]
    const float* __restrict__ b_ih,  // [12]
    const float* __restrict__ b_hh,  // [12]
    float* __restrict__ out)         // [B*T*4] then h_n [B*4]
{
    __shared__ __align__(16) float gi_s[2][TC][NB][12];   // 98304 B
    __shared__ __align__(16) float out_s[2][NB][OS_W];    // 36864 B

    const int tid  = threadIdx.x;
    const int wid  = tid >> 6;
    const int lane = tid & 63;
    const int b0   = blockIdx.x * NB;

    const float NL2E = -1.4426950408889634f;  // -log2(e)
    const float P2   =  2.8853900817779268f;  //  2*log2(e)

    if ((wid % 3) != 2) {
        // ================= recurrence wave (2 per SIMD) =================
        const int r  = wid - (wid + 1) / 3;   // rec index 0..7
        const int qd = lane >> 2;             // chain slot 0..15
        const int j  = lane & 3;              // hidden unit
        const int bl = r * 16 + qd;           // local batch 0..127

        // w_hh rows permuted so index m multiplies h_{(j+m)&3} (DPP order)
        float whr[4], whz[4], whn[4];
        #pragma unroll
        for (int m = 0; m < 4; ++m) {
            int k = (j + m) & 3;
            whr[m] = NL2E * w_hh[j * 4 + k];
            whz[m] = NL2E * w_hh[(4 + j) * 4 + k];
            whn[m] = P2   * w_hh[(8 + j) * 4 + k];
        }
        const float bhn = P2 * b_hh[8 + j];

        float h = 0.0f;
        __syncthreads();   // gi chunk 0 ready

        for (int c = 0; c < 128; ++c) {
            const float* gb = &gi_s[c & 1][0][bl][j];
            float*       os = &out_s[c & 1][bl][0];

            // stage the chunk's gi into regs (bulk ds_reads, off the h-chain)
            float sr[TC], sz[TC], sn[TC];
            #pragma unroll
            for (int t = 0; t < TC; ++t) {
                const float* gt = gb + t * (NB * 12);
                sr[t] = gt[0];
                sz[t] = gt[4];
                sn[t] = gt[8];
            }

            #pragma unroll
            for (int t = 0; t < TC; ++t) {
                float h1 = dpp_rot<0x39>(h);
                float h2 = dpp_rot<0x4E>(h);
                float h3 = dpp_rot<0x93>(h);
                // depth-3 trees (bit-identical to R3)
                float gr = fmaf(whr[0], h, whr[1] * h1) + fmaf(whr[2], h2, whr[3] * h3);
                float gz = fmaf(whz[0], h, whz[1] * h1) + fmaf(whz[2], h2, whz[3] * h3);
                float gn = fmaf(whn[0], h, whn[1] * h1) + fmaf(whn[2], h2, fmaf(whn[3], h3, bhn));

                float rr = vrcp(1.0f + vexp2(sr[t] + gr));   // sigmoid (pre-scaled)
                float z  = vrcp(1.0f + vexp2(sz[t] + gz));
                // off-chain prep so only one fma follows the final rcp:
                float omz   = 1.0f - z;
                float szh   = fmaf(z, h, omz);    // z*h + (1-z)
                float m2omz = -2.0f * omz;
                // n-path: u = 1/(1+e^{2a}); h' = omz*(1-2u)+z*h = fma(m2omz,u,szh)
                float u = vrcp(1.0f + vexp2(fmaf(rr, gn, sn[t])));
                h = fmaf(m2omz, u, szh);

                os[t * 4 + j] = h;
            }
            __syncthreads();
        }
        // h_n tail
        out[33554432LL + (long long)(b0 + bl) * 4 + j] = h;

    } else {
        // ================= helper wave (1 per SIMD) =================
        const int hw   = wid / 3;             // helper index 0..3
        const int cell = hw * 64 + lane;      // 0..255
        const int bb   = cell >> 1;           // batch slot 0..127
        const int half = cell & 1;            // t-half of chunk (0..1), 4 t's each

        // all 12 w_ih rows + fused biases (identical math to R3)
        float wr[4][3], wz[4][3], wn[4][3];
        float cbr[4], cbz[4], cbn[4];
        #pragma unroll
        for (int jj = 0; jj < 4; ++jj) {
            #pragma unroll
            for (int k = 0; k < 3; ++k) {
                wr[jj][k] = NL2E * w_ih[jj * 3 + k];
                wz[jj][k] = NL2E * w_ih[(4 + jj) * 3 + k];
                wn[jj][k] = P2   * w_ih[(8 + jj) * 3 + k];
            }
            cbr[jj] = NL2E * (b_ih[jj]     + b_hh[jj]);
            cbz[jj] = NL2E * (b_ih[4 + jj] + b_hh[4 + jj]);
            cbn[jj] = P2   * b_ih[8 + jj];
        }

        const float* xp0 = x + (long long)(b0 + bb) * 3072 + half * 12;

        // compute gi for one chunk into buf, from 12 x-values in 3 float4 regs
        auto compute_gi = [&](int cc, float4 a, float4 b, float4 e, int buf) {
            float xs[12] = { a.x, a.y, a.z, a.w, b.x, b.y, b.z, b.w, e.x, e.y, e.z, e.w };
            #pragma unroll
            for (int dt = 0; dt < 4; ++dt) {
                float x0 = xs[dt * 3], x1 = xs[dt * 3 + 1], x2 = xs[dt * 3 + 2];
                float g[12];
                #pragma unroll
                for (int jj = 0; jj < 4; ++jj) {
                    g[jj]     = fmaf(wr[jj][0], x0, fmaf(wr[jj][1], x1, fmaf(wr[jj][2], x2, cbr[jj])));
                    g[4 + jj] = fmaf(wz[jj][0], x0, fmaf(wz[jj][1], x1, fmaf(wz[jj][2], x2, cbz[jj])));
                    g[8 + jj] = fmaf(wn[jj][0], x0, fmaf(wn[jj][1], x1, fmaf(wn[jj][2], x2, cbn[jj])));
                }
                float4* gp = (float4*)&gi_s[buf][half * 4 + dt][bb][0];
                gp[0] = make_float4(g[0], g[1], g[2],  g[3]);
                gp[1] = make_float4(g[4], g[5], g[6],  g[7]);
                gp[2] = make_float4(g[8], g[9], g[10], g[11]);
            }
        };
        // flush chunk cc from buf to global (coalesced 128B per 8-lane group)
        auto flush_out = [&](int cc, int buf) {
            #pragma unroll
            for (int u = 0; u < 4; ++u) {
                int f  = u * 256 + cell;
                int fb = f >> 3;          // batch 0..127
                int ft = f & 7;           // t 0..7
                float4 v = *(const float4*)&out_s[buf][fb][ft * 4];
                *(float4*)(out + (long long)(b0 + fb) * 4096 + (long long)(cc * TC + ft) * 4) = v;
            }
        };

        // prologue: x(0) -> gi chunk 0; prefetch x(1)
        float4 nx0 = *(const float4*)(xp0 + 0);
        float4 nx1 = *(const float4*)(xp0 + 4);
        float4 nx2 = *(const float4*)(xp0 + 8);
        compute_gi(0, nx0, nx1, nx2, 0);
        nx0 = *(const float4*)(xp0 + 24);
        nx1 = *(const float4*)(xp0 + 28);
        nx2 = *(const float4*)(xp0 + 32);
        __syncthreads();   // release chunk 0

        for (int c = 0; c < 128; ++c) {
            float4 t0, t1, t2;
            if (c < 126) {                        // issue x(c+2) loads early
                const float* xp = xp0 + (long long)(c + 2) * 24;
                t0 = *(const float4*)(xp + 0);
                t1 = *(const float4*)(xp + 4);
                t2 = *(const float4*)(xp + 8);
            }
            if (c < 127) compute_gi(c + 1, nx0, nx1, nx2, (c + 1) & 1);
            if (c > 0)   flush_out(c - 1, (c - 1) & 1);
            if (c < 126) { nx0 = t0; nx1 = t1; nx2 = t2; }
            __syncthreads();
        }
        flush_out(127, 1);
    }
}

extern "C" void kernel_launch(void* const* d_in, const int* in_sizes, int n_in,
                              void* d_out, int out_size, void* d_ws, size_t ws_size,
                              hipStream_t stream) {
    const float* x    = (const float*)d_in[0];
    const float* w_ih = (const float*)d_in[1];
    const float* w_hh = (const float*)d_in[2];
    const float* b_ih = (const float*)d_in[3];
    const float* b_hh = (const float*)d_in[4];
    float* out = (float*)d_out;

    dim3 grid(64), block(768);   // 64 blocks x 128 batches = 8192; 12 waves/block
    gru_kernel<<<grid, block, 0, stream>>>(x, w_ih, w_hh, b_ih, b_hh, out);
}

// Round 3
// 283.627 us; speedup vs baseline: 1.2429x; 1.2429x over previous
//
#include <hip/hip_runtime.h>

// GRU: B=8192, T=1024, I=3, H=4, fp32.
// R6: back to R3 shell (latency-optimal structure: 512 blk x 2 waves, 16 b/blk).
//   R3/R4/R5 fit: chain is latency-bound, L ~= 68 + 4*E, E(trans dep lat) ~= 54.
//   Only lever is shortening L:
//   (a) r-round & u-round: 1/(1+2^a) via V'=exp2(-|a|) (free modifiers) +
//       Chebyshev poly for 1/(1+V') on [0,1]; sel g vs V'*g by sign(a).
//       Removes add1+rcp (62cy) for poly (32-40cy). z-gate stays exact (off-path).
//   (b) aR/aZ trees rebalanced with sr/sz as fma leaf (40->32cy).
//   (c) gi triple-buffer + register prefetch of next chunk (kills per-chunk
//       ds_read stall); helper runs 2 chunks ahead.
// Weights pre-scaled (-log2e for r,z; 2log2e for n).

#define TC 16
#define GI_TS 192          // gi stride per t: 16 batches * 12
#define OS_STRIDE 68       // out_s row: TC*4 + 4 pad

template<int CTRL>
__device__ __forceinline__ float dpp_rot(float v) {
    int i = __builtin_bit_cast(int, v);
    int r = __builtin_amdgcn_mov_dpp(i, CTRL, 0xf, 0xf, true);
    return __builtin_bit_cast(float, r);
}
__device__ __forceinline__ float vrcp(float x)  { return __builtin_amdgcn_rcpf(x); }
__device__ __forceinline__ float vexp2(float x) { return __builtin_amdgcn_exp2f(x); }

__global__ __launch_bounds__(128) void gru_kernel(
    const float* __restrict__ x,     // [B, T, 3]
    const float* __restrict__ w_ih,  // [12, 3]
    const float* __restrict__ w_hh,  // [12, 4]
    const float* __restrict__ b_ih,  // [12]
    const float* __restrict__ b_hh,  // [12]
    float* __restrict__ out)         // [B*T*4] then h_n [B*4]
{
    __shared__ float gi_s[3][TC * GI_TS];       // 36.0 KB (triple buffer)
    __shared__ float out_s[2][16 * OS_STRIDE];  //  8.5 KB

    const int tid = threadIdx.x;
    const int b0  = blockIdx.x * 16;

    const float NL2E = -1.4426950408889634f;  // -log2(e)
    const float P2   =  2.8853900817779268f;  //  2*log2(e)

    if (tid < 64) {
        // ================= recurrence wave =================
        const int q = tid >> 2;   // batch slot 0..15
        const int j = tid & 3;    // hidden unit

        // w_hh rows permuted so index m multiplies h_{(j+m)&3} (DPP order)
        float whr[4], whz[4], whn[4];
        #pragma unroll
        for (int m = 0; m < 4; ++m) {
            int k = (j + m) & 3;
            whr[m] = NL2E * w_hh[j * 4 + k];
            whz[m] = NL2E * w_hh[(4 + j) * 4 + k];
            whn[m] = P2   * w_hh[(8 + j) * 4 + k];
        }
        const float bhn = P2 * b_hh[8 + j];

        float h = 0.0f;
        float srA[TC], szA[TC], snA[TC], srB[TC], szB[TC], snB[TC];

        auto stage = [&](int c, float* SR, float* SZ, float* SN) {
            const float* gb = &gi_s[c % 3][q * 12 + j];
            #pragma unroll
            for (int t = 0; t < TC; ++t) {
                SR[t] = gb[t * GI_TS];
                SZ[t] = gb[t * GI_TS + 4];
                SN[t] = gb[t * GI_TS + 8];
            }
        };

        auto run16 = [&](int c, const float* SR, const float* SZ, const float* SN) {
            float* os = &out_s[c & 1][q * OS_STRIDE];
            #pragma unroll
            for (int t = 0; t < TC; ++t) {
                float h1 = dpp_rot<0x39>(h);
                float h2 = dpp_rot<0x4E>(h);
                float h3 = dpp_rot<0x93>(h);

                // balanced trees, sr/sz as fma leaf (path: dpp+mul, +add, +add)
                float aR = (fmaf(whr[0], h, SR[t]) + whr[1] * h1)
                         + fmaf(whr[2], h2, whr[3] * h3);
                float aZ = (fmaf(whz[0], h, SZ[t]) + whz[1] * h1)
                         + fmaf(whz[2], h2, whz[3] * h3);
                float gn = fmaf(whn[0], h, whn[1] * h1)
                         + fmaf(whn[2], h2, fmaf(whn[3], h3, bhn));

                // r = 1/(1+2^aR): V' = 2^(-|aR|) (free mods), deg-4 poly for
                // 1/(1+V') on [0,1] (Chebyshev, |err|<=2.5e-4); sel by sign.
                float Vr = vexp2(-__builtin_fabsf(aR));
                float gr = fmaf(Vr, fmaf(Vr, fmaf(Vr, fmaf(Vr,
                               0.156856f, -0.542276f), 0.871966f), -0.986113f), 0.999751f);
                float r  = (aR > 0.0f) ? Vr * gr : gr;

                // z exact (off critical path)
                float z = vrcp(1.0f + vexp2(aZ));
                float omz   = 1.0f - z;
                float szh   = fmaf(z, h, omz);    // z*h + (1-z)
                float m2omz = -2.0f * omz;

                // u = 1/(1+2^e), e = r*gn + sn; deg-5 poly (|err|<=4e-5)
                float e  = fmaf(r, gn, SN[t]);
                float Vn = vexp2(-__builtin_fabsf(e));
                float gu = fmaf(Vn, fmaf(Vn, fmaf(Vn, fmaf(Vn, fmaf(Vn,
                               -0.10764288f, 0.4259632f), -0.7777448f),
                               0.956062f), -0.996625f), 0.99996124f);
                float u  = (e > 0.0f) ? Vn * gu : gu;

                // h' = omz*(1-2u) + z*h = fma(-2omz, u, szh)
                h = fmaf(m2omz, u, szh);

                os[t * 4 + j] = h;
            }
        };

        __syncthreads();          // helper wrote chunks 0 and 1
        stage(0, srA, szA, snA);

        for (int c = 0; c < 64; c += 2) {
            stage(c + 1, srB, szB, snB);     // reads issued ~1 chunk early
            run16(c, srA, szA, snA);
            __syncthreads();
            if (c + 2 < 64) stage(c + 2, srA, szA, snA);
            run16(c + 1, srB, szB, snB);
            __syncthreads();
        }
        // h_n tail
        out[33554432LL + (long long)(b0 + q) * 4 + j] = h;

    } else {
        // ================= helper wave =================
        const int hl = tid - 64;
        const int bb = hl >> 2;   // batch slot 0..15
        const int s  = hl & 3;    // t-slice 0..3

        // all 12 w_ih rows + fused biases (wave-uniform -> scalar regs)
        float wr[4][3], wz[4][3], wn[4][3];
        float cbr[4], cbz[4], cbn[4];
        #pragma unroll
        for (int jj = 0; jj < 4; ++jj) {
            #pragma unroll
            for (int k = 0; k < 3; ++k) {
                wr[jj][k] = NL2E * w_ih[jj * 3 + k];
                wz[jj][k] = NL2E * w_ih[(4 + jj) * 3 + k];
                wn[jj][k] = P2   * w_ih[(8 + jj) * 3 + k];
            }
            cbr[jj] = NL2E * (b_ih[jj]     + b_hh[jj]);
            cbz[jj] = NL2E * (b_ih[4 + jj] + b_hh[4 + jj]);
            cbn[jj] = P2   * b_ih[8 + jj];
        }

        const long long xbase = (long long)(b0 + bb) * 3072;

        // gi compute for chunk cc into buf
        auto compute_gi = [&](int cc, float* buf) {
            #pragma unroll
            for (int k = 0; k < 4; ++k) {
                int tl = k * 4 + s;                       // 0..15
                const float* xp = x + xbase + (long long)(cc * TC + tl) * 3;
                float x0 = xp[0], x1 = xp[1], x2 = xp[2];
                float* gp = &buf[tl * GI_TS + bb * 12];
                #pragma unroll
                for (int jj = 0; jj < 4; ++jj) {
                    gp[jj]     = fmaf(wr[jj][0], x0, fmaf(wr[jj][1], x1, fmaf(wr[jj][2], x2, cbr[jj])));
                    gp[4 + jj] = fmaf(wz[jj][0], x0, fmaf(wz[jj][1], x1, fmaf(wz[jj][2], x2, cbz[jj])));
                    gp[8 + jj] = fmaf(wn[jj][0], x0, fmaf(wn[jj][1], x1, fmaf(wn[jj][2], x2, cbn[jj])));
                }
            }
        };
        // flush chunk cc from buf to global (64 floats per batch row)
        auto flush_out = [&](int cc, const float* buf) {
            #pragma unroll
            for (int u = 0; u < 4; ++u) {
                int f   = u * 64 + hl;
                int bbf = f >> 4;
                int idx = f & 15;
                float4 v = *(const float4*)&buf[bbf * OS_STRIDE + idx * 4];
                *(float4*)(out + (long long)(b0 + bbf) * 4096 + cc * 64 + idx * 4) = v;
            }
        };

        // prologue: two chunks ahead (triple buffer)
        compute_gi(0, gi_s[0]);
        compute_gi(1, gi_s[1]);
        __syncthreads();   // release chunks 0,1

        for (int c = 0; c < 64; ++c) {
            if (c < 62) compute_gi(c + 2, gi_s[(c + 2) % 3]);
            if (c > 0)  flush_out(c - 1, out_s[(c - 1) & 1]);
            __syncthreads();
        }
        flush_out(63, out_s[1]);
    }
}

extern "C" void kernel_launch(void* const* d_in, const int* in_sizes, int n_in,
                              void* d_out, int out_size, void* d_ws, size_t ws_size,
                              hipStream_t stream) {
    const float* x    = (const float*)d_in[0];
    const float* w_ih = (const float*)d_in[1];
    const float* w_hh = (const float*)d_in[2];
    const float* b_ih = (const float*)d_in[3];
    const float* b_hh = (const float*)d_in[4];
    float* out = (float*)d_out;

    dim3 grid(512), block(128);   // 512 blocks x 16 batches = 8192; 2 waves/block
    gru_kernel<<<grid, block, 0, stream>>>(x, w_ih, w_hh, b_ih, b_hh, out);
}

// Round 4
// 273.646 us; speedup vs baseline: 1.2883x; 1.0365x over previous
//
#include <hip/hip_runtime.h>

// GRU: B=8192, T=1024, I=3, H=4, fp32.
// R7: hand-scheduled step. R6 proved wall = issue + chain-latency with ZERO
//   overlap (wall tracked issue 1:1). Fix: pin off-path work into the
//   transcendental latency shadows with sched_barrier(0) fences:
//     ep/eq shadow <- z-tree, z-exp2, gn-tree
//     r-rcp shadow <- z-rcp
//     en shadow    <- z epilogue (omz, szh, m2)
//     h->dpp edge  <- os write
//   Plus one on-path cut: r via exp-product split
//     r = rcp(fma(2^p, 2^q, 1)), p/q = tree halves  (-20cy: earlier exp2,
//     tree-add and 1+ add folded into one fma). ~1ulp numerics diff.
//   Math otherwise identical to R3 (exact rcp sigmoids, no polys).
// Shell: R3 structure (512 blk x 2 waves, 16 batches/blk) + R6 triple-buffer gi.
// Weights pre-scaled (-log2e for r,z; 2log2e for n).

#define TC 16
#define GI_TS 192          // gi stride per t: 16 batches * 12
#define OS_STRIDE 68       // out_s row: TC*4 + 4 pad

template<int CTRL>
__device__ __forceinline__ float dpp_rot(float v) {
    int i = __builtin_bit_cast(int, v);
    int r = __builtin_amdgcn_mov_dpp(i, CTRL, 0xf, 0xf, true);
    return __builtin_bit_cast(float, r);
}
__device__ __forceinline__ float vrcp(float x)  { return __builtin_amdgcn_rcpf(x); }
__device__ __forceinline__ float vexp2(float x) { return __builtin_amdgcn_exp2f(x); }
#define SB() __builtin_amdgcn_sched_barrier(0)

__global__ __launch_bounds__(128) void gru_kernel(
    const float* __restrict__ x,     // [B, T, 3]
    const float* __restrict__ w_ih,  // [12, 3]
    const float* __restrict__ w_hh,  // [12, 4]
    const float* __restrict__ b_ih,  // [12]
    const float* __restrict__ b_hh,  // [12]
    float* __restrict__ out)         // [B*T*4] then h_n [B*4]
{
    __shared__ float gi_s[3][TC * GI_TS];       // 36.0 KB (triple buffer)
    __shared__ float out_s[2][16 * OS_STRIDE];  //  8.5 KB

    const int tid = threadIdx.x;
    const int b0  = blockIdx.x * 16;

    const float NL2E = -1.4426950408889634f;  // -log2(e)
    const float P2   =  2.8853900817779268f;  //  2*log2(e)

    if (tid < 64) {
        // ================= recurrence wave =================
        const int q = tid >> 2;   // batch slot 0..15
        const int j = tid & 3;    // hidden unit

        // w_hh rows permuted so index m multiplies h_{(j+m)&3} (DPP order)
        float whr[4], whz[4], whn[4];
        #pragma unroll
        for (int m = 0; m < 4; ++m) {
            int k = (j + m) & 3;
            whr[m] = NL2E * w_hh[j * 4 + k];
            whz[m] = NL2E * w_hh[(4 + j) * 4 + k];
            whn[m] = P2   * w_hh[(8 + j) * 4 + k];
        }
        const float bhn = P2 * b_hh[8 + j];

        float h = 0.0f;
        float srA[TC], szA[TC], snA[TC], srB[TC], szB[TC], snB[TC];

        auto stage = [&](int c, float* SR, float* SZ, float* SN) {
            const float* gb = &gi_s[c % 3][q * 12 + j];
            #pragma unroll
            for (int t = 0; t < TC; ++t) {
                SR[t] = gb[t * GI_TS];
                SZ[t] = gb[t * GI_TS + 4];
                SN[t] = gb[t * GI_TS + 8];
            }
        };

        auto run16 = [&](int c, const float* SR, const float* SZ, const float* SN) {
            float* os = &out_s[c & 1][q * OS_STRIDE];
            #pragma unroll
            for (int t = 0; t < TC; ++t) {
                // ---- G0/G1: dpps + r-path front; start exp2 ASAP ----
                float h1 = dpp_rot<0x39>(h);
                float h2 = dpp_rot<0x4E>(h);
                float h3 = dpp_rot<0x93>(h);
                float p  = fmaf(whr[1], h1, fmaf(whr[0], h, SR[t]));
                float qv = fmaf(whr[3], h3, whr[2] * h2);
                float ep = vexp2(p);
                float eq = vexp2(qv);
                SB();
                // ---- G2: fillers under ep/eq latency ----
                float aZ = (fmaf(whz[0], h, SZ[t]) + whz[1] * h1)
                         + fmaf(whz[2], h2, whz[3] * h3);
                float ez = vexp2(aZ);
                float gn = fmaf(whn[0], h, whn[1] * h1)
                         + fmaf(whn[2], h2, fmaf(whn[3], h3, bhn));
                SB();
                // ---- G3: r (tree-add and 1+ folded into the fma) ----
                float r  = vrcp(fmaf(ep, eq, 1.0f));
                SB();
                // ---- G4: filler under r's rcp latency ----
                float z  = vrcp(1.0f + ez);
                SB();
                // ---- G5: n-gate argument + exp2 ----
                float e  = fmaf(r, gn, SN[t]);
                float en = vexp2(e);
                SB();
                // ---- G6: fillers under en latency: z epilogue ----
                float omz = 1.0f - z;
                float szh = fmaf(z, h, omz);      // z*h + (1-z)
                float m2  = -2.0f * omz;
                SB();
                // ---- G7: u ----
                float u  = vrcp(1.0f + en);
                SB();
                // ---- G8: close the step; os write fills h->dpp edge ----
                h = fmaf(m2, u, szh);
                os[t * 4 + j] = h;
            }
        };

        __syncthreads();          // helper wrote chunks 0 and 1
        stage(0, srA, szA, snA);

        for (int c = 0; c < 64; c += 2) {
            stage(c + 1, srB, szB, snB);     // reads issued ~1 chunk early
            run16(c, srA, szA, snA);
            __syncthreads();
            if (c + 2 < 64) stage(c + 2, srA, szA, snA);
            run16(c + 1, srB, szB, snB);
            __syncthreads();
        }
        // h_n tail
        out[33554432LL + (long long)(b0 + q) * 4 + j] = h;

    } else {
        // ================= helper wave =================
        const int hl = tid - 64;
        const int bb = hl >> 2;   // batch slot 0..15
        const int s  = hl & 3;    // t-slice 0..3

        // all 12 w_ih rows + fused biases (wave-uniform -> scalar regs)
        float wr[4][3], wz[4][3], wn[4][3];
        float cbr[4], cbz[4], cbn[4];
        #pragma unroll
        for (int jj = 0; jj < 4; ++jj) {
            #pragma unroll
            for (int k = 0; k < 3; ++k) {
                wr[jj][k] = NL2E * w_ih[jj * 3 + k];
                wz[jj][k] = NL2E * w_ih[(4 + jj) * 3 + k];
                wn[jj][k] = P2   * w_ih[(8 + jj) * 3 + k];
            }
            cbr[jj] = NL2E * (b_ih[jj]     + b_hh[jj]);
            cbz[jj] = NL2E * (b_ih[4 + jj] + b_hh[4 + jj]);
            cbn[jj] = P2   * b_ih[8 + jj];
        }

        const long long xbase = (long long)(b0 + bb) * 3072;

        // gi compute for chunk cc into buf
        auto compute_gi = [&](int cc, float* buf) {
            #pragma unroll
            for (int k = 0; k < 4; ++k) {
                int tl = k * 4 + s;                       // 0..15
                const float* xp = x + xbase + (long long)(cc * TC + tl) * 3;
                float x0 = xp[0], x1 = xp[1], x2 = xp[2];
                float* gp = &buf[tl * GI_TS + bb * 12];
                #pragma unroll
                for (int jj = 0; jj < 4; ++jj) {
                    gp[jj]     = fmaf(wr[jj][0], x0, fmaf(wr[jj][1], x1, fmaf(wr[jj][2], x2, cbr[jj])));
                    gp[4 + jj] = fmaf(wz[jj][0], x0, fmaf(wz[jj][1], x1, fmaf(wz[jj][2], x2, cbz[jj])));
                    gp[8 + jj] = fmaf(wn[jj][0], x0, fmaf(wn[jj][1], x1, fmaf(wn[jj][2], x2, cbn[jj])));
                }
            }
        };
        // flush chunk cc from buf to global (64 floats per batch row)
        auto flush_out = [&](int cc, const float* buf) {
            #pragma unroll
            for (int u = 0; u < 4; ++u) {
                int f   = u * 64 + hl;
                int bbf = f >> 4;
                int idx = f & 15;
                float4 v = *(const float4*)&buf[bbf * OS_STRIDE + idx * 4];
                *(float4*)(out + (long long)(b0 + bbf) * 4096 + cc * 64 + idx * 4) = v;
            }
        };

        // prologue: two chunks ahead (triple buffer)
        compute_gi(0, gi_s[0]);
        compute_gi(1, gi_s[1]);
        __syncthreads();   // release chunks 0,1

        for (int c = 0; c < 64; ++c) {
            if (c < 62) compute_gi(c + 2, gi_s[(c + 2) % 3]);
            if (c > 0)  flush_out(c - 1, out_s[(c - 1) & 1]);
            __syncthreads();
        }
        flush_out(63, out_s[1]);
    }
}

extern "C" void kernel_launch(void* const* d_in, const int* in_sizes, int n_in,
                              void* d_out, int out_size, void* d_ws, size_t ws_size,
                              hipStream_t stream) {
    const float* x    = (const float*)d_in[0];
    const float* w_ih = (const float*)d_in[1];
    const float* w_hh = (const float*)d_in[2];
    const float* b_ih = (const float*)d_in[3];
    const float* b_hh = (const float*)d_in[4];
    float* out = (float*)d_out;

    dim3 grid(512), block(128);   // 512 blocks x 16 batches = 8192; 2 waves/block
    gru_kernel<<<grid, block, 0, stream>>>(x, w_ih, w_hh, b_ih, b_hh, out);
}